// Round 4
// baseline (920.555 us; speedup 1.0000x reference)
//
#include <hip/hip_runtime.h>
#include <cmath>

#define HDIM 2048
#define H4   (HDIM / 4)     // 512 float4 per row
#define NEXP 64
#define TTOT 16384
#define KSPLIT 8
#define KBLK (HDIM / KSPLIT)    // 256 k per block
#define BK   16
#define NTILE (KBLK / BK)       // 16 K-tiles per block
#define BMB  256                // tokens per gemm block
#define LDA  260                // 256+4: scatter stores 2-way (free), reads 2-way
#define LDB  68
#define LDS_SC 65

// ws layout: [0..63] prob_acc, [64..127] gate_acc, [128..] partials
#define WS_PARTIAL_OFF 128
// partial[rt 0..255][kg 0..7][64*64] : rt = global_token/64
#define PARTIAL_FLOATS ((size_t)(TTOT / 64) * KSPLIT * 64 * NEXP)  // 8.39M

// ===========================================================================
// Kernel 1: one block = 256 tokens x 64 experts x K=256 slice.
// 8x8 fp32 microtile per thread (LDS:FMA ratio 1.5 vs round-3's 3.0).
// A+B staged transposed in LDS (double-buffered), grid 64x8 = 2 blocks/CU.
// ===========================================================================
__global__ __launch_bounds__(256, 3) void router_gemm_k(
    const float* __restrict__ x,        // [T, H]
    const float* __restrict__ gw,       // [E, H]
    float* __restrict__ partial)
{
    __shared__ float a_s[2][BK][LDA];   // [k][token]
    __shared__ float b_s[2][BK][LDB];   // [k][expert]

    const int tid  = threadIdx.x;
    const int lane = tid & 63;
    const int wave = tid >> 6;
    const int eg   = lane & 7;          // expert group: experts 8eg..8eg+7
    const int tgl  = lane >> 3;
    const int tg   = wave * 8 + tgl;    // token group 0..31: tokens 8tg..8tg+7
    const int tb   = blockIdx.x;        // 0..63
    const int kg   = blockIdx.y;        // 0..7
    const int T0   = tb * BMB;
    const int kb4  = kg * (KBLK / 4);   // float4 k-offset of this slice

    const int r = tid >> 2;             // staging row 0..63
    const int c = tid & 3;              // staging float4 col 0..3

    const float4* __restrict__ x4 = reinterpret_cast<const float4*>(x) + (size_t)T0 * H4 + kb4;
    const float4* __restrict__ g4 = reinterpret_cast<const float4*>(gw) + kb4;

    float acc[8][8] = {};

    // A: thread stages rows r+64j (j=0..3), float4 col c; B: row r, col c.
    // Scatter-store banks: (16c + 4u + r) mod 32 -> 2-way alias (free).
#define LOAD_TILE(TT, PA, PB) do {                                             \
        const int _k4 = (TT) * (BK / 4);                                       \
        _Pragma("unroll")                                                      \
        for (int j = 0; j < 4; ++j)                                            \
            PA[j] = x4[(size_t)(r + 64 * j) * H4 + _k4 + c];                   \
        PB = g4[(size_t)r * H4 + _k4 + c];                                     \
    } while (0)

#define STORE_TILE(BUFI, PA, PB) do {                                          \
        _Pragma("unroll")                                                      \
        for (int j = 0; j < 4; ++j) {                                          \
            const float _t[4] = {PA[j].x, PA[j].y, PA[j].z, PA[j].w};          \
            _Pragma("unroll")                                                  \
            for (int u = 0; u < 4; ++u)                                        \
                a_s[BUFI][c * 4 + u][r + 64 * j] = _t[u];                      \
        }                                                                      \
        const float _t2[4] = {PB.x, PB.y, PB.z, PB.w};                         \
        _Pragma("unroll")                                                      \
        for (int u = 0; u < 4; ++u)                                            \
            b_s[BUFI][c * 4 + u][r] = _t2[u];                                  \
    } while (0)

    {
        float4 pa[4]; float4 pb;
        LOAD_TILE(0, pa, pb);
        STORE_TILE(0, pa, pb);
    }
    __syncthreads();

    int buf = 0;
    for (int tt = 0; tt < NTILE; ++tt) {
        float4 na[4]; float4 nb;
        const bool has_next = (tt + 1 < NTILE);
        if (has_next) LOAD_TILE(tt + 1, na, nb);

        #pragma unroll
        for (int kk = 0; kk < BK; ++kk) {
            const float4 a0 = *reinterpret_cast<const float4*>(&a_s[buf][kk][tg * 8]);
            const float4 a1 = *reinterpret_cast<const float4*>(&a_s[buf][kk][tg * 8 + 4]);
            const float4 b0 = *reinterpret_cast<const float4*>(&b_s[buf][kk][eg * 8]);
            const float4 b1 = *reinterpret_cast<const float4*>(&b_s[buf][kk][eg * 8 + 4]);
            const float af[8] = {a0.x, a0.y, a0.z, a0.w, a1.x, a1.y, a1.z, a1.w};
            const float bf[8] = {b0.x, b0.y, b0.z, b0.w, b1.x, b1.y, b1.z, b1.w};
            #pragma unroll
            for (int i = 0; i < 8; ++i)
                #pragma unroll
                for (int j = 0; j < 8; ++j)
                    acc[i][j] = fmaf(af[i], bf[j], acc[i][j]);
        }

        if (has_next) STORE_TILE(buf ^ 1, na, nb);
        __syncthreads();
        buf ^= 1;
    }
#undef LOAD_TILE
#undef STORE_TILE

    // write partials: token t_loc = tg*8+i, experts 8eg..8eg+7
    #pragma unroll
    for (int i = 0; i < 8; ++i) {
        const int t_loc = tg * 8 + i;
        const int rt    = tb * 4 + (t_loc >> 6);     // 64-token tile id
        const int trow  = t_loc & 63;
        float4* pout = reinterpret_cast<float4*>(
            partial + ((size_t)rt * KSPLIT + kg) * (64 * NEXP) + (size_t)trow * NEXP);
        pout[eg * 2]     = make_float4(acc[i][0], acc[i][1], acc[i][2], acc[i][3]);
        pout[eg * 2 + 1] = make_float4(acc[i][4], acc[i][5], acc[i][6], acc[i][7]);
    }
}

// ===========================================================================
// Kernel 2: sum 8 K-split partials + bias, top-2 + softmax + aux partials.
// ===========================================================================
__global__ __launch_bounds__(256) void router_reduce(
    const float* __restrict__ partial,
    const float* __restrict__ rep,
    const float* __restrict__ loads,
    const float* __restrict__ counts,
    const int*   __restrict__ total_dec,
    float* __restrict__ out_w,
    float* __restrict__ out_idx,
    float* __restrict__ prob_acc,
    float* __restrict__ gate_acc)
{
    __shared__ float sc_s[64][LDS_SC];
    __shared__ float bias_s[NEXP];
    __shared__ float m_s[64], z_s[64];
    __shared__ int   i1_s[64], i2_s[64];

    const int tid = threadIdx.x;
    const int rt  = blockIdx.x;        // 64-token tile 0..255
    const int t0  = rt * 64;

    if (tid < NEXP) {
        float L = logf((float)(*total_dec) + 1.0f);
        bias_s[tid] = 0.1f * rep[tid] - 0.1f * loads[tid]
                    + 0.1f * sqrtf(L / (counts[tid] + 1e-10f));
    }
    __syncthreads();

    const float* p = partial + (size_t)rt * KSPLIT * (64 * NEXP);
    #pragma unroll
    for (int o = 0; o < (64 * NEXP) / 256; ++o) {
        const int idx = o * 256 + tid;
        float s = 0.0f;
        #pragma unroll
        for (int g = 0; g < KSPLIT; ++g)
            s += p[(size_t)g * (64 * NEXP) + idx];
        sc_s[idx >> 6][idx & 63] = s + bias_s[idx & 63];
    }
    __syncthreads();

    // pass 1: per-token top-2 (strict '>' keeps lowest index), softmax weights
    if (tid < 64) {
        const int t = tid;
        float m1 = -INFINITY, m2 = -INFINITY;
        int   i1 = 0, i2 = 0;
        for (int e = 0; e < NEXP; ++e) {
            const float s = sc_s[t][e];
            if (s > m1)      { m2 = m1; i2 = i1; m1 = s; i1 = e; }
            else if (s > m2) { m2 = s; i2 = e; }
        }
        float z = 0.0f;
        for (int e = 0; e < NEXP; ++e) z += expf(sc_s[t][e] - m1);

        const float e2  = expf(m2 - m1);
        const float inv = 1.0f / (1.0f + e2);
        const int   gt  = t0 + t;
        reinterpret_cast<float2*>(out_w)[gt]   = make_float2(inv, e2 * inv);
        reinterpret_cast<float2*>(out_idx)[gt] = make_float2((float)i1, (float)i2);
        m_s[t] = m1; z_s[t] = z; i1_s[t] = i1; i2_s[t] = i2;
    }
    __syncthreads();

    // pass 2: per-expert partial sums for aux loss
    if (tid < NEXP) {
        const int e = tid;
        float ps = 0.0f, gs = 0.0f;
        for (int t = 0; t < 64; ++t) {
            ps += expf(sc_s[t][e] - m_s[t]) / z_s[t];
            gs += (float)((i1_s[t] == e) + (i2_s[t] == e));
        }
        atomicAdd(&prob_acc[e], ps);
        atomicAdd(&gate_acc[e], gs);
    }
}

// ===========================================================================
// Fallback (round-1 proven): single fused kernel, used only if ws too small.
// ===========================================================================
#define BKF  32
#define LDAF (64 + 4)
__global__ __launch_bounds__(256) void router_main(
    const float* __restrict__ x,
    const float* __restrict__ gw,
    const float* __restrict__ rep,
    const float* __restrict__ loads,
    const float* __restrict__ counts,
    const int*   __restrict__ total_dec,
    float* __restrict__ out_w,
    float* __restrict__ out_idx,
    float* __restrict__ prob_acc,
    float* __restrict__ gate_acc)
{
    __shared__ float a_s[2][BKF][LDAF];
    __shared__ float b_s[2][BKF][LDAF];
    __shared__ float sc_s[64][LDS_SC];
    __shared__ float bias_s[NEXP];
    __shared__ float m_s[64], z_s[64];
    __shared__ int   i1_s[64], i2_s[64];

    const int tid = threadIdx.x;
    const int tx  = tid & 15;
    const int ty  = tid >> 4;
    const int r0  = tid >> 3;
    const int c4  = tid & 7;
    const int t0  = blockIdx.x * 64;

    if (tid < NEXP) {
        float L = logf((float)(*total_dec) + 1.0f);
        bias_s[tid] = 0.1f * rep[tid] - 0.1f * loads[tid]
                    + 0.1f * sqrtf(L / (counts[tid] + 1e-10f));
    }

    const float4* __restrict__ x4 = reinterpret_cast<const float4*>(x) + (size_t)t0 * H4;
    const float4* __restrict__ g4 = reinterpret_cast<const float4*>(gw);

    float acc[4][4] = {};

#define STORE_TILE(BUFI, A0, A1, B0, B1) do {                                  \
        float _t0[4] = {(A0).x, (A0).y, (A0).z, (A0).w};                       \
        float _t1[4] = {(A1).x, (A1).y, (A1).z, (A1).w};                       \
        float _t2[4] = {(B0).x, (B0).y, (B0).z, (B0).w};                       \
        float _t3[4] = {(B1).x, (B1).y, (B1).z, (B1).w};                       \
        _Pragma("unroll")                                                      \
        for (int u = 0; u < 4; ++u) {                                          \
            a_s[BUFI][c4 * 4 + u][r0]      = _t0[u];                           \
            a_s[BUFI][c4 * 4 + u][r0 + 32] = _t1[u];                           \
            b_s[BUFI][c4 * 4 + u][r0]      = _t2[u];                           \
            b_s[BUFI][c4 * 4 + u][r0 + 32] = _t3[u];                           \
        } } while (0)

    {
        float4 a0 = x4[(size_t)r0 * H4 + c4];
        float4 a1 = x4[(size_t)(r0 + 32) * H4 + c4];
        float4 b0 = g4[(size_t)r0 * H4 + c4];
        float4 b1 = g4[(size_t)(r0 + 32) * H4 + c4];
        STORE_TILE(0, a0, a1, b0, b1);
    }
    __syncthreads();

    int buf = 0;
    for (int it = 0; it < HDIM / BKF; ++it) {
        float4 na0, na1, nb0, nb1;
        const bool has_next = (it + 1 < HDIM / BKF);
        if (has_next) {
            const int k4 = (it + 1) * (BKF / 4);
            na0 = x4[(size_t)r0 * H4 + k4 + c4];
            na1 = x4[(size_t)(r0 + 32) * H4 + k4 + c4];
            nb0 = g4[(size_t)r0 * H4 + k4 + c4];
            nb1 = g4[(size_t)(r0 + 32) * H4 + k4 + c4];
        }
        #pragma unroll
        for (int kk = 0; kk < BKF; ++kk) {
            const float4 afv = *reinterpret_cast<const float4*>(&a_s[buf][kk][ty * 4]);
            const float4 bfv = *reinterpret_cast<const float4*>(&b_s[buf][kk][tx * 4]);
            const float af[4] = {afv.x, afv.y, afv.z, afv.w};
            const float bf[4] = {bfv.x, bfv.y, bfv.z, bfv.w};
            #pragma unroll
            for (int i = 0; i < 4; ++i)
                #pragma unroll
                for (int j = 0; j < 4; ++j)
                    acc[i][j] = fmaf(af[i], bf[j], acc[i][j]);
        }
        if (has_next) STORE_TILE(buf ^ 1, na0, na1, nb0, nb1);
        __syncthreads();
        buf ^= 1;
    }
#undef STORE_TILE

    #pragma unroll
    for (int i = 0; i < 4; ++i)
        #pragma unroll
        for (int j = 0; j < 4; ++j)
            sc_s[ty * 4 + i][tx * 4 + j] = acc[i][j] + bias_s[tx * 4 + j];
    __syncthreads();

    if (tid < 64) {
        const int t = tid;
        float m1 = -INFINITY, m2 = -INFINITY;
        int   i1 = 0, i2 = 0;
        for (int e = 0; e < NEXP; ++e) {
            const float s = sc_s[t][e];
            if (s > m1)      { m2 = m1; i2 = i1; m1 = s; i1 = e; }
            else if (s > m2) { m2 = s; i2 = e; }
        }
        float z = 0.0f;
        for (int e = 0; e < NEXP; ++e) z += expf(sc_s[t][e] - m1);
        const float e2  = expf(m2 - m1);
        const float inv = 1.0f / (1.0f + e2);
        const int   gt  = t0 + t;
        reinterpret_cast<float2*>(out_w)[gt]   = make_float2(inv, e2 * inv);
        reinterpret_cast<float2*>(out_idx)[gt] = make_float2((float)i1, (float)i2);
        m_s[t] = m1; z_s[t] = z; i1_s[t] = i1; i2_s[t] = i2;
    }
    __syncthreads();

    if (tid < NEXP) {
        const int e = tid;
        float ps = 0.0f, gs = 0.0f;
        for (int t = 0; t < 64; ++t) {
            ps += expf(sc_s[t][e] - m_s[t]) / z_s[t];
            gs += (float)((i1_s[t] == e) + (i2_s[t] == e));
        }
        atomicAdd(&prob_acc[e], ps);
        atomicAdd(&gate_acc[e], gs);
    }
}

__global__ void router_aux(const float* __restrict__ prob_acc,
                           const float* __restrict__ gate_acc,
                           float* __restrict__ out_aux)
{
    const float invT = 1.0f / (float)TTOT;
    const int e = threadIdx.x;
    float v = (gate_acc[e] * invT) * (prob_acc[e] * invT);
    #pragma unroll
    for (int off = 32; off > 0; off >>= 1)
        v += __shfl_down(v, off);
    if (e == 0) out_aux[0] = v * (float)NEXP;
}

extern "C" void kernel_launch(void* const* d_in, const int* in_sizes, int n_in,
                              void* d_out, int out_size, void* d_ws, size_t ws_size,
                              hipStream_t stream)
{
    const float* x      = (const float*)d_in[0];
    const float* gw     = (const float*)d_in[1];
    const float* rep    = (const float*)d_in[2];
    const float* loads  = (const float*)d_in[3];
    const float* counts = (const float*)d_in[4];
    const int*   total  = (const int*)d_in[5];

    float* out     = (float*)d_out;
    float* out_w   = out;            // [16384*2] routing weights
    float* out_idx = out + 32768;    // [16384*2] expert indices as float
    float* out_aux = out + 65536;    // [1] aux loss

    float* prob_acc = (float*)d_ws;
    float* gate_acc = prob_acc + NEXP;
    float* partial  = (float*)d_ws + WS_PARTIAL_OFF;

    const size_t ws_needed = (WS_PARTIAL_OFF + PARTIAL_FLOATS) * sizeof(float);

    hipMemsetAsync(d_ws, 0, WS_PARTIAL_OFF * sizeof(float), stream);

    if (ws_size >= ws_needed) {
        router_gemm_k<<<dim3(TTOT / BMB, KSPLIT), dim3(256), 0, stream>>>(x, gw, partial);
        router_reduce<<<dim3(TTOT / 64), dim3(256), 0, stream>>>(
            partial, rep, loads, counts, total, out_w, out_idx, prob_acc, gate_acc);
    } else {
        router_main<<<dim3(TTOT / 64), dim3(256), 0, stream>>>(
            x, gw, rep, loads, counts, total, out_w, out_idx, prob_acc, gate_acc);
    }
    router_aux<<<dim3(1), dim3(64), 0, stream>>>(prob_acc, gate_acc, out_aux);
}

// Round 5
// 232.904 us; speedup vs baseline: 3.9525x; 3.9525x over previous
//
#include <hip/hip_runtime.h>
#include <cmath>

#define HDIM 2048
#define H4   (HDIM / 4)         // 512 float4 per row
#define NEXP 64
#define TTOT 16384
#define KSPLIT 2
#define KBLK (HDIM / KSPLIT)    // 1024 k per block
#define BKC  64                 // k per staged chunk
#define NCHUNK (KBLK / BKC)     // 16
#define BTOK 64                 // tokens per block
#define LDT  72                 // padded k-stride (shorts): 2-way bank alias only
#define LDS_SC 65

// ws layout: [0..63] prob_acc, [64..127] gate_acc, [128..] partials
#define WS_PARTIAL_OFF 128
#define PARTIAL_FLOATS ((size_t)(TTOT / BTOK) * KSPLIT * BTOK * NEXP)  // 2.1M

typedef short  bf16x8 __attribute__((ext_vector_type(8)));
typedef float  f32x4  __attribute__((ext_vector_type(4)));

// round-to-nearest-even fp32 -> bf16 (bit trick); also returns the value back
// in fp32 so the residual (exact, Sterbenz) can be computed.
__device__ __forceinline__ short f2bf_rn(float f, float* back) {
    unsigned u = __float_as_uint(f);
    unsigned r = (u + 0x7fffu + ((u >> 16) & 1u)) & 0xffff0000u;
    *back = __uint_as_float(r);
    return (short)(r >> 16);
}

// ===========================================================================
// Kernel 1: MFMA GEMM, exact 3-way bf16 split of fp32 (x = h+m+l exactly).
// scores = hH + hM + mH + hL + mM + lH  (dropped terms ~2^-23 rel -> ~1e-7).
// Block: 64 tokens x 64 experts x K=1024 (grid 256 x 2). 4 waves, each wave
// a 32x32 quadrant = 2x2 MFMA tiles of 16x16x32_bf16. fp32 partials to ws.
// ===========================================================================
__global__ __launch_bounds__(256, 2) void router_gemm_mfma(
    const float* __restrict__ x,        // [T, H]
    const float* __restrict__ gw,       // [E, H]  (= B^T layout, E x K)
    float* __restrict__ partial)        // [256][2][64*64]
{
    __shared__ short aT[3][BTOK][LDT];  // x  tile: h/m/l variants, [token][k]
    __shared__ short bT[3][NEXP][LDT];  // gw tile: h/m/l variants, [expert][k]

    const int tid  = threadIdx.x;
    const int lane = tid & 63;
    const int quad = lane >> 4;
    const int l15  = lane & 15;
    const int w    = tid >> 6;          // wave 0..3
    const int wm   = w & 1;             // token half  (32 rows)
    const int wn   = w >> 1;            // expert half (32 cols)
    const int tb   = blockIdx.x;        // token block 0..255
    const int kg   = blockIdx.y;        // K half 0..1
    const int T0   = tb * BTOK;

    // staging role: thread t handles row t>>2, float4 cols (t&3)+4j, j=0..3
    const int srow = tid >> 2;
    const int scol = tid & 3;

    const float4* __restrict__ x4 = reinterpret_cast<const float4*>(x);
    const float4* __restrict__ g4 = reinterpret_cast<const float4*>(gw);

    f32x4 acc[2][2];
    #pragma unroll
    for (int i = 0; i < 2; ++i)
        #pragma unroll
        for (int j = 0; j < 2; ++j)
            acc[i][j] = (f32x4){0.f, 0.f, 0.f, 0.f};

    float4 xa[4], xb[4];   // prefetched fp32 chunk data (consumed before reload)

#define LOAD_CHUNK(CH) do {                                                    \
        const int _c4b = kg * (H4 / 2) + (CH) * (BKC / 4);                     \
        _Pragma("unroll")                                                      \
        for (int j = 0; j < 4; ++j) {                                          \
            xa[j] = x4[(size_t)(T0 + srow) * H4 + _c4b + scol + 4 * j];        \
            xb[j] = g4[(size_t)srow * H4 + _c4b + scol + 4 * j];               \
        } } while (0)

    // convert one float4 into h/m/l short4s and store to tile T at [row][kloc]
#define SPLIT_STORE(TILE, ROW, KLOC, FV) do {                                  \
        const float _f[4] = {(FV).x, (FV).y, (FV).z, (FV).w};                  \
        short _h[4], _m[4], _l[4];                                             \
        _Pragma("unroll")                                                      \
        for (int u = 0; u < 4; ++u) {                                          \
            float _b0, _b1, _b2;                                               \
            _h[u] = f2bf_rn(_f[u], &_b0);                                      \
            float _r1 = _f[u] - _b0;                                           \
            _m[u] = f2bf_rn(_r1, &_b1);                                        \
            float _r2 = _r1 - _b1;                                             \
            _l[u] = f2bf_rn(_r2, &_b2);                                        \
        }                                                                      \
        *reinterpret_cast<short4*>(&TILE[0][ROW][KLOC]) =                      \
            make_short4(_h[0], _h[1], _h[2], _h[3]);                           \
        *reinterpret_cast<short4*>(&TILE[1][ROW][KLOC]) =                      \
            make_short4(_m[0], _m[1], _m[2], _m[3]);                           \
        *reinterpret_cast<short4*>(&TILE[2][ROW][KLOC]) =                      \
            make_short4(_l[0], _l[1], _l[2], _l[3]);                           \
    } while (0)

    LOAD_CHUNK(0);

    for (int ch = 0; ch < NCHUNK; ++ch) {
        // ---- convert prefetched regs -> LDS (regs free after this) ----
        #pragma unroll
        for (int j = 0; j < 4; ++j) {
            const int kloc = 4 * (scol + 4 * j);
            SPLIT_STORE(aT, srow, kloc, xa[j]);
            SPLIT_STORE(bT, srow, kloc, xb[j]);
        }
        __syncthreads();

        if (ch + 1 < NCHUNK) LOAD_CHUNK(ch + 1);   // overlaps MFMA below

        // ---- MFMA over this chunk: 2 K=32 steps ----
        #pragma unroll
        for (int k0 = 0; k0 < BKC; k0 += 32) {
            const int kf = k0 + quad * 8;
            bf16x8 ah[2], am[2], al[2], bh[2], bm[2], bl[2];
            #pragma unroll
            for (int mt = 0; mt < 2; ++mt) {
                const int row = 32 * wm + 16 * mt + l15;
                ah[mt] = *reinterpret_cast<const bf16x8*>(&aT[0][row][kf]);
                am[mt] = *reinterpret_cast<const bf16x8*>(&aT[1][row][kf]);
                al[mt] = *reinterpret_cast<const bf16x8*>(&aT[2][row][kf]);
            }
            #pragma unroll
            for (int nt = 0; nt < 2; ++nt) {
                const int row = 32 * wn + 16 * nt + l15;
                bh[nt] = *reinterpret_cast<const bf16x8*>(&bT[0][row][kf]);
                bm[nt] = *reinterpret_cast<const bf16x8*>(&bT[1][row][kf]);
                bl[nt] = *reinterpret_cast<const bf16x8*>(&bT[2][row][kf]);
            }
            #pragma unroll
            for (int mt = 0; mt < 2; ++mt)
                #pragma unroll
                for (int nt = 0; nt < 2; ++nt) {
                    f32x4 c = acc[mt][nt];
                    c = __builtin_amdgcn_mfma_f32_16x16x32_bf16(ah[mt], bh[nt], c, 0, 0, 0);
                    c = __builtin_amdgcn_mfma_f32_16x16x32_bf16(ah[mt], bm[nt], c, 0, 0, 0);
                    c = __builtin_amdgcn_mfma_f32_16x16x32_bf16(am[mt], bh[nt], c, 0, 0, 0);
                    c = __builtin_amdgcn_mfma_f32_16x16x32_bf16(ah[mt], bl[nt], c, 0, 0, 0);
                    c = __builtin_amdgcn_mfma_f32_16x16x32_bf16(am[mt], bm[nt], c, 0, 0, 0);
                    c = __builtin_amdgcn_mfma_f32_16x16x32_bf16(al[mt], bh[nt], c, 0, 0, 0);
                    acc[mt][nt] = c;
                }
        }
        __syncthreads();   // LDS free for next chunk's staging
    }
#undef LOAD_CHUNK
#undef SPLIT_STORE

    // ---- write fp32 partials (C/D layout: row = quad*4+reg, col = lane&15) ----
    float* pbase = partial + ((size_t)tb * KSPLIT + kg) * (BTOK * NEXP);
    #pragma unroll
    for (int mt = 0; mt < 2; ++mt)
        #pragma unroll
        for (int nt = 0; nt < 2; ++nt) {
            const int e = 32 * wn + 16 * nt + l15;
            #pragma unroll
            for (int r = 0; r < 4; ++r) {
                const int t_loc = 32 * wm + 16 * mt + quad * 4 + r;
                pbase[(size_t)t_loc * NEXP + e] = acc[mt][nt][r];
            }
        }
}

// ===========================================================================
// Kernel 2: sum 2 K-split partials + bias, top-2 + softmax + aux partials.
// (round-3 proven structure)
// ===========================================================================
__global__ __launch_bounds__(256) void router_reduce(
    const float* __restrict__ partial,
    const float* __restrict__ rep,
    const float* __restrict__ loads,
    const float* __restrict__ counts,
    const int*   __restrict__ total_dec,
    float* __restrict__ out_w,
    float* __restrict__ out_idx,
    float* __restrict__ prob_acc,
    float* __restrict__ gate_acc)
{
    __shared__ float sc_s[BTOK][LDS_SC];
    __shared__ float bias_s[NEXP];
    __shared__ float m_s[BTOK], z_s[BTOK];
    __shared__ int   i1_s[BTOK], i2_s[BTOK];

    const int tid = threadIdx.x;
    const int rt  = blockIdx.x;        // 64-token tile 0..255
    const int t0  = rt * BTOK;

    if (tid < NEXP) {
        float L = logf((float)(*total_dec) + 1.0f);
        bias_s[tid] = 0.1f * rep[tid] - 0.1f * loads[tid]
                    + 0.1f * sqrtf(L / (counts[tid] + 1e-10f));
    }
    __syncthreads();

    const float* p = partial + (size_t)rt * KSPLIT * (BTOK * NEXP);
    #pragma unroll
    for (int o = 0; o < (BTOK * NEXP) / 256; ++o) {
        const int idx = o * 256 + tid;
        float s = p[idx] + p[BTOK * NEXP + idx];
        sc_s[idx >> 6][idx & 63] = s + bias_s[idx & 63];
    }
    __syncthreads();

    // pass 1: per-token top-2 (strict '>' keeps lowest index), softmax weights
    if (tid < BTOK) {
        const int t = tid;
        float m1 = -INFINITY, m2 = -INFINITY;
        int   i1 = 0, i2 = 0;
        for (int e = 0; e < NEXP; ++e) {
            const float s = sc_s[t][e];
            if (s > m1)      { m2 = m1; i2 = i1; m1 = s; i1 = e; }
            else if (s > m2) { m2 = s; i2 = e; }
        }
        float z = 0.0f;
        for (int e = 0; e < NEXP; ++e) z += expf(sc_s[t][e] - m1);

        const float e2  = expf(m2 - m1);
        const float inv = 1.0f / (1.0f + e2);
        const int   gt  = t0 + t;
        reinterpret_cast<float2*>(out_w)[gt]   = make_float2(inv, e2 * inv);
        reinterpret_cast<float2*>(out_idx)[gt] = make_float2((float)i1, (float)i2);
        m_s[t] = m1; z_s[t] = z; i1_s[t] = i1; i2_s[t] = i2;
    }
    __syncthreads();

    // pass 2: per-expert partial sums for aux loss
    if (tid < NEXP) {
        const int e = tid;
        float ps = 0.0f, gs = 0.0f;
        for (int t = 0; t < BTOK; ++t) {
            ps += expf(sc_s[t][e] - m_s[t]) / z_s[t];
            gs += (float)((i1_s[t] == e) + (i2_s[t] == e));
        }
        atomicAdd(&prob_acc[e], ps);
        atomicAdd(&gate_acc[e], gs);
    }
}

// ===========================================================================
// Fallback (round-1/3 proven): single fused fp32 kernel, if ws too small.
// ===========================================================================
#define BKF  32
#define LDAF (64 + 4)
__global__ __launch_bounds__(256) void router_main(
    const float* __restrict__ x,
    const float* __restrict__ gw,
    const float* __restrict__ rep,
    const float* __restrict__ loads,
    const float* __restrict__ counts,
    const int*   __restrict__ total_dec,
    float* __restrict__ out_w,
    float* __restrict__ out_idx,
    float* __restrict__ prob_acc,
    float* __restrict__ gate_acc)
{
    __shared__ float a_s[2][BKF][LDAF];
    __shared__ float b_s[2][BKF][LDAF];
    __shared__ float sc_s[64][LDS_SC];
    __shared__ float bias_s[NEXP];
    __shared__ float m_s[64], z_s[64];
    __shared__ int   i1_s[64], i2_s[64];

    const int tid = threadIdx.x;
    const int tx  = tid & 15;
    const int ty  = tid >> 4;
    const int r0  = tid >> 3;
    const int c4  = tid & 7;
    const int t0  = blockIdx.x * 64;

    if (tid < NEXP) {
        float L = logf((float)(*total_dec) + 1.0f);
        bias_s[tid] = 0.1f * rep[tid] - 0.1f * loads[tid]
                    + 0.1f * sqrtf(L / (counts[tid] + 1e-10f));
    }

    const float4* __restrict__ x4 = reinterpret_cast<const float4*>(x) + (size_t)t0 * H4;
    const float4* __restrict__ g4 = reinterpret_cast<const float4*>(gw);

    float acc[4][4] = {};

#define STORE_TILE(BUFI, A0, A1, B0, B1) do {                                  \
        float _t0[4] = {(A0).x, (A0).y, (A0).z, (A0).w};                       \
        float _t1[4] = {(A1).x, (A1).y, (A1).z, (A1).w};                       \
        float _t2[4] = {(B0).x, (B0).y, (B0).z, (B0).w};                       \
        float _t3[4] = {(B1).x, (B1).y, (B1).z, (B1).w};                       \
        _Pragma("unroll")                                                      \
        for (int u = 0; u < 4; ++u) {                                          \
            a_s[BUFI][c4 * 4 + u][r0]      = _t0[u];                           \
            a_s[BUFI][c4 * 4 + u][r0 + 32] = _t1[u];                           \
            b_s[BUFI][c4 * 4 + u][r0]      = _t2[u];                           \
            b_s[BUFI][c4 * 4 + u][r0 + 32] = _t3[u];                           \
        } } while (0)

    {
        float4 a0 = x4[(size_t)r0 * H4 + c4];
        float4 a1 = x4[(size_t)(r0 + 32) * H4 + c4];
        float4 b0 = g4[(size_t)r0 * H4 + c4];
        float4 b1 = g4[(size_t)(r0 + 32) * H4 + c4];
        STORE_TILE(0, a0, a1, b0, b1);
    }
    __syncthreads();

    int buf = 0;
    for (int it = 0; it < HDIM / BKF; ++it) {
        float4 na0, na1, nb0, nb1;
        const bool has_next = (it + 1 < HDIM / BKF);
        if (has_next) {
            const int k4 = (it + 1) * (BKF / 4);
            na0 = x4[(size_t)r0 * H4 + k4 + c4];
            na1 = x4[(size_t)(r0 + 32) * H4 + k4 + c4];
            nb0 = g4[(size_t)r0 * H4 + k4 + c4];
            nb1 = g4[(size_t)(r0 + 32) * H4 + k4 + c4];
        }
        #pragma unroll
        for (int kk = 0; kk < BKF; ++kk) {
            const float4 afv = *reinterpret_cast<const float4*>(&a_s[buf][kk][ty * 4]);
            const float4 bfv = *reinterpret_cast<const float4*>(&b_s[buf][kk][tx * 4]);
            const float af[4] = {afv.x, afv.y, afv.z, afv.w};
            const float bf[4] = {bfv.x, bfv.y, bfv.z, bfv.w};
            #pragma unroll
            for (int i = 0; i < 4; ++i)
                #pragma unroll
                for (int j = 0; j < 4; ++j)
                    acc[i][j] = fmaf(af[i], bf[j], acc[i][j]);
        }
        if (has_next) STORE_TILE(buf ^ 1, na0, na1, nb0, nb1);
        __syncthreads();
        buf ^= 1;
    }
#undef STORE_TILE

    #pragma unroll
    for (int i = 0; i < 4; ++i)
        #pragma unroll
        for (int j = 0; j < 4; ++j)
            sc_s[ty * 4 + i][tx * 4 + j] = acc[i][j] + bias_s[tx * 4 + j];
    __syncthreads();

    if (tid < 64) {
        const int t = tid;
        float m1 = -INFINITY, m2 = -INFINITY;
        int   i1 = 0, i2 = 0;
        for (int e = 0; e < NEXP; ++e) {
            const float s = sc_s[t][e];
            if (s > m1)      { m2 = m1; i2 = i1; m1 = s; i1 = e; }
            else if (s > m2) { m2 = s; i2 = e; }
        }
        float z = 0.0f;
        for (int e = 0; e < NEXP; ++e) z += expf(sc_s[t][e] - m1);
        const float e2  = expf(m2 - m1);
        const float inv = 1.0f / (1.0f + e2);
        const int   gt  = t0 + t;
        reinterpret_cast<float2*>(out_w)[gt]   = make_float2(inv, e2 * inv);
        reinterpret_cast<float2*>(out_idx)[gt] = make_float2((float)i1, (float)i2);
        m_s[t] = m1; z_s[t] = z; i1_s[t] = i1; i2_s[t] = i2;
    }
    __syncthreads();

    if (tid < NEXP) {
        const int e = tid;
        float ps = 0.0f, gs = 0.0f;
        for (int t = 0; t < 64; ++t) {
            ps += expf(sc_s[t][e] - m_s[t]) / z_s[t];
            gs += (float)((i1_s[t] == e) + (i2_s[t] == e));
        }
        atomicAdd(&prob_acc[e], ps);
        atomicAdd(&gate_acc[e], gs);
    }
}

__global__ void router_aux(const float* __restrict__ prob_acc,
                           const float* __restrict__ gate_acc,
                           float* __restrict__ out_aux)
{
    const float invT = 1.0f / (float)TTOT;
    const int e = threadIdx.x;
    float v = (gate_acc[e] * invT) * (prob_acc[e] * invT);
    #pragma unroll
    for (int off = 32; off > 0; off >>= 1)
        v += __shfl_down(v, off);
    if (e == 0) out_aux[0] = v * (float)NEXP;
}

extern "C" void kernel_launch(void* const* d_in, const int* in_sizes, int n_in,
                              void* d_out, int out_size, void* d_ws, size_t ws_size,
                              hipStream_t stream)
{
    const float* x      = (const float*)d_in[0];
    const float* gw     = (const float*)d_in[1];
    const float* rep    = (const float*)d_in[2];
    const float* loads  = (const float*)d_in[3];
    const float* counts = (const float*)d_in[4];
    const int*   total  = (const int*)d_in[5];

    float* out     = (float*)d_out;
    float* out_w   = out;            // [16384*2] routing weights
    float* out_idx = out + 32768;    // [16384*2] expert indices as float
    float* out_aux = out + 65536;    // [1] aux loss

    float* prob_acc = (float*)d_ws;
    float* gate_acc = prob_acc + NEXP;
    float* partial  = (float*)d_ws + WS_PARTIAL_OFF;

    const size_t ws_needed = (WS_PARTIAL_OFF + PARTIAL_FLOATS) * sizeof(float);

    hipMemsetAsync(d_ws, 0, WS_PARTIAL_OFF * sizeof(float), stream);

    if (ws_size >= ws_needed) {
        router_gemm_mfma<<<dim3(TTOT / BTOK, KSPLIT), dim3(256), 0, stream>>>(x, gw, partial);
        router_reduce<<<dim3(TTOT / BTOK), dim3(256), 0, stream>>>(
            partial, rep, loads, counts, total, out_w, out_idx, prob_acc, gate_acc);
    } else {
        router_main<<<dim3(TTOT / 64), dim3(256), 0, stream>>>(
            x, gw, rep, loads, counts, total, out_w, out_idx, prob_acc, gate_acc);
    }
    router_aux<<<dim3(1), dim3(64), 0, stream>>>(prob_acc, gate_acc, out_aux);
}